// Round 3
// baseline (623.520 us; speedup 1.0000x reference)
//
#include <hip/hip_runtime.h>
#include <math.h>

typedef unsigned short u16;
typedef __attribute__((ext_vector_type(8))) short bf16x8;
typedef __attribute__((ext_vector_type(8))) unsigned short u16x8;
typedef __attribute__((ext_vector_type(4))) float f32x4;

__device__ __forceinline__ u16 f2bf(float f){
  union { float f; unsigned u; } c; c.f = f;
  unsigned u = c.u;
  return (u16)((u + 0x7fffu + ((u >> 16) & 1u)) >> 16);
}
__device__ __forceinline__ float bf2f(u16 h){
  union { unsigned u; float f; } c; c.u = ((unsigned)h) << 16;
  return c.f;
}
__device__ __forceinline__ void gload_lds16(const void* g, void* l){
  __builtin_amdgcn_global_load_lds((const __attribute__((address_space(1))) void*)g,
                                   (__attribute__((address_space(3))) void*)l, 16, 0, 0);
}
// XOR swizzle within a 1024B LDS row (attention kernels)
__device__ __forceinline__ int swz(int row, int bc){
  return (row << 10) + (bc ^ ((row & 7) << 4));
}

// ---------------- weight transpose + f32->bf16 : in [K][N] f32 -> out [N][K] bf16
__global__ void transpose_cvt(const float* __restrict__ in, u16* __restrict__ out, int K, int N){
  __shared__ float tile[32][33];
  int n0 = blockIdx.x << 5, k0 = blockIdx.y << 5;
  int tx = threadIdx.x, ty = threadIdx.y;
  #pragma unroll
  for (int r = 0; r < 32; r += 8)
    tile[ty + r][tx] = in[(size_t)(k0 + ty + r) * N + n0 + tx];
  __syncthreads();
  #pragma unroll
  for (int r = 0; r < 32; r += 8)
    out[(size_t)(n0 + ty + r) * K + k0 + tx] = f2bf(tile[tx][ty + r]);
}

__global__ void concat3(const float* __restrict__ a, const float* __restrict__ b,
                        const float* __restrict__ c, float* __restrict__ o){
  int i = blockIdx.x * 256 + threadIdx.x;
  o[i] = i < 1024 ? a[i] : (i < 2048 ? b[i - 1024] : c[i - 2048]);
}

// ---------------- layernorm: f32 [rows][1024] -> bf16 [rows][1024]
__device__ __forceinline__ float blockReduce(float v, float* ws){
  #pragma unroll
  for (int m = 1; m < 64; m <<= 1) v += __shfl_xor(v, m, 64);
  int w = threadIdx.x >> 6;
  __syncthreads();
  if ((threadIdx.x & 63) == 0) ws[w] = v;
  __syncthreads();
  return ws[0] + ws[1] + ws[2] + ws[3];
}

struct U16x4 { u16 x, y, z, w; };

__global__ __launch_bounds__(256) void ln_kernel(const float* __restrict__ in, const float* __restrict__ g,
    const float* __restrict__ be, u16* __restrict__ out){
  __shared__ float ws[4];
  int row = blockIdx.x;
  const float4 v = ((const float4*)(in + ((size_t)row << 10)))[threadIdx.x];
  float s = v.x + v.y + v.z + v.w;
  s = blockReduce(s, ws);
  float mean = s * (1.f / 1024.f);
  float dx = v.x - mean, dy = v.y - mean, dz = v.z - mean, dw = v.w - mean;
  float s2 = dx*dx + dy*dy + dz*dz + dw*dw;
  s2 = blockReduce(s2, ws);
  float rstd = rsqrtf(s2 * (1.f / 1024.f) + 1e-5f);
  float4 gv = ((const float4*)g)[threadIdx.x];
  float4 bv = ((const float4*)be)[threadIdx.x];
  U16x4 ov;
  ov.x = f2bf(dx * rstd * gv.x + bv.x);
  ov.y = f2bf(dy * rstd * gv.y + bv.y);
  ov.z = f2bf(dz * rstd * gv.z + bv.z);
  ov.w = f2bf(dw * rstd * gv.w + bv.w);
  ((U16x4*)(out + ((size_t)row << 10)))[threadIdx.x] = ov;
}

// ---------------- 256x256 8-phase bf16 GEMM (T1+T2+T3+T4+T5)
// A [M][K] bf16, Bt [N][K] bf16. BK=64, 8 waves (2M x 4N), per-wave 128x64.
// LDS: buf{0,1}: A 32KiB + B 32KiB each; +16KiB dump = 144 KiB.
// Sync derivation (per-wave load queue, 2 loads/STAGE):
//   prologue issues 12 loads; vmcnt(8)+barrier publishes T0.Ah0,T0.Bh0.
//   End-of-phase waits (then barrier, so next phase's readers are safe):
//   ph1: vmcnt(6) retires T0.Ah1,T0.Bh1 ; ph4: vmcnt(8) retires T1.Ah0,T1.Bh0
//   ph5: vmcnt(6) retires T1.Ah1,T1.Bh1 ; ph8: vmcnt(8) retires T2.Ah0,T2.Bh0
//   Every region overwrite's last reader is >=1 phase earlier (barrier between).

#define BAR() asm volatile("s_barrier" ::: "memory")

template<int B, int QM, int QN, int VN, typename F>
__device__ __forceinline__ void do_phase(const char* lds, const int (&aoff)[2], const int (&boff)[2],
                                         f32x4 (&acc)[8][4], F&& stg){
  bf16x8 af[4][2], bv[2][2];
  const char* Ar = lds + B*65536 + QM*16384;
  const char* Br = lds + B*65536 + 32768 + QN*16384;
  #pragma unroll
  for (int fi = 0; fi < 4; ++fi)
    #pragma unroll
    for (int ks = 0; ks < 2; ++ks)
      af[fi][ks] = *(const bf16x8*)(Ar + fi*2048 + aoff[ks]);
  #pragma unroll
  for (int fj = 0; fj < 2; ++fj)
    #pragma unroll
    for (int ks = 0; ks < 2; ++ks)
      bv[fj][ks] = *(const bf16x8*)(Br + fj*2048 + boff[ks]);
  stg();
  BAR();
  __builtin_amdgcn_s_setprio(1);
  #pragma unroll
  for (int fi = 0; fi < 4; ++fi)
    #pragma unroll
    for (int fj = 0; fj < 2; ++fj){
      acc[QM*4+fi][QN*2+fj] = __builtin_amdgcn_mfma_f32_16x16x32_bf16(af[fi][0], bv[fj][0], acc[QM*4+fi][QN*2+fj], 0, 0, 0);
      acc[QM*4+fi][QN*2+fj] = __builtin_amdgcn_mfma_f32_16x16x32_bf16(af[fi][1], bv[fj][1], acc[QM*4+fi][QN*2+fj], 0, 0, 0);
    }
  __builtin_amdgcn_s_setprio(0);
  if constexpr (VN >= 0)
    asm volatile("s_waitcnt vmcnt(%0)" :: "n"(VN) : "memory");
  BAR();
}

// EPI 0: bf16 scatter to q/k/v [3][B*NH, S, HD] (+bias)
// EPI 1: f32 = acc + bias + add
// EPI 2: bf16 = gelu(acc + bias)
template<int EPI>
__global__ __launch_bounds__(512, 2) void gemm8(
    const u16* __restrict__ A, const u16* __restrict__ Bt,
    const float* __restrict__ bias, const float* __restrict__ add,
    void* __restrict__ out, int M, int N, int K)
{
  __shared__ char lds[147456];
  const int NT = K >> 6;
  const int NI = NT >> 1;
  const int nbx = N >> 8;
  // bijective XCD swizzle (m204)
  const int nwg = gridDim.x, orig = blockIdx.x;
  const int q = nwg >> 3, r = nwg & 7, x = orig & 7;
  const int wg = (x < r ? x * (q + 1) : r * (q + 1) + (x - r) * q) + (orig >> 3);
  const int bx = wg % nbx, by = wg / nbx;
  const int m0 = by << 8, n0 = bx << 8;

  const int tid = threadIdx.x, wave = tid >> 6, lane = tid & 63;
  const int wr = (wave >> 2) & 1, wc = wave & 3;
  const int lcol = lane & 15, lrow4 = lane >> 4;

  int aoff[2], boff[2];
  #pragma unroll
  for (int ks = 0; ks < 2; ++ks){
    const int chunk = (ks*4 + lrow4) ^ (lane & 7);
    aoff[ks] = (wr*64 + lcol)*128 + chunk*16;
    boff[ks] = (wc*32 + lcol)*128 + chunk*16;
  }

  // STAGE half h (rows h*128..+127) of K-tile tt. Pre-swizzled SOURCE +
  // linear LDS dest (rule #21): LDS chunk c holds global chunk c ^ (row&7).
  // Out-of-range tiles stage into the dump region (keeps vmcnt exact in tail).
  auto STAGE = [&](const u16* Mat, int rbase, int isB, int h, int tt){
    const int rb = (tt < NT) ? ((tt & 1) * 65536 + isB * 32768 + h * 16384) : 131072;
    const int tc = (tt < NT) ? tt : NT - 1;
    #pragma unroll
    for (int s = 0; s < 2; ++s){
      const int o = (tid + s*512) << 4;
      const int row = o >> 7;
      const int c = (o >> 4) & 7;
      const char* src = (const char*)(Mat + (size_t)(rbase + h*128 + row) * K + (size_t)tc * 64)
                        + ((c ^ (row & 7)) << 4);
      gload_lds16(src, (char*)lds + rb + o);
    }
  };

  f32x4 acc[8][4] = {};

  // prologue: T0.Ah0, T0.Bh0, T0.Ah1, T0.Bh1, T1.Ah0, T1.Bh0
  STAGE(A,  m0, 0, 0, 0);
  STAGE(Bt, n0, 1, 0, 0);
  STAGE(A,  m0, 0, 1, 0);
  STAGE(Bt, n0, 1, 1, 0);
  STAGE(A,  m0, 0, 0, 1);
  STAGE(Bt, n0, 1, 0, 1);
  asm volatile("s_waitcnt vmcnt(8)" ::: "memory");  // T0.Ah0,T0.Bh0 landed
  BAR();

  for (int i = 0; i < NI; ++i) {
    const int T = 2*i;
    do_phase<0,0,0, 6>(lds, aoff, boff, acc, [&]{ STAGE(A,  m0, 0, 1, T+1); });
    do_phase<0,0,1,-1>(lds, aoff, boff, acc, [&]{ STAGE(Bt, n0, 1, 1, T+1); });
    do_phase<0,1,0,-1>(lds, aoff, boff, acc, [&]{ STAGE(A,  m0, 0, 0, T+2); });
    do_phase<0,1,1, 8>(lds, aoff, boff, acc, [&]{ STAGE(Bt, n0, 1, 0, T+2); });
    do_phase<1,0,0, 6>(lds, aoff, boff, acc, [&]{ STAGE(A,  m0, 0, 1, T+2); });
    do_phase<1,0,1,-1>(lds, aoff, boff, acc, [&]{ STAGE(Bt, n0, 1, 1, T+2); });
    do_phase<1,1,0,-1>(lds, aoff, boff, acc, [&]{ STAGE(A,  m0, 0, 0, T+3); });
    do_phase<1,1,1, 8>(lds, aoff, boff, acc, [&]{ STAGE(Bt, n0, 1, 0, T+3); });
  }

  // launder epilogue pointers so their loads cannot be hoisted into the
  // K-loop (would corrupt the hand-counted vmcnt queue)
  { size_t bp = (size_t)bias, ap = (size_t)add;
    asm volatile("" : "+v"(bp), "+v"(ap));
    bias = (const float*)bp; add = (const float*)ap; }

  #pragma unroll
  for (int mi = 0; mi < 8; ++mi) {
    const int gmb = m0 + (mi>>2)*128 + wr*64 + (mi&3)*16 + lrow4*4;
    #pragma unroll
    for (int ni = 0; ni < 4; ++ni) {
      const int gn = n0 + (ni>>1)*128 + wc*32 + (ni&1)*16 + lcol;
      const float bs = bias[gn];
      #pragma unroll
      for (int rr = 0; rr < 4; ++rr) {
        const int gm = gmb + rr;
        float v = acc[mi][ni][rr] + bs;
        if constexpr (EPI == 0) {
          const int which = gn >> 10, g = gn & 1023;
          const int b = gm >> 11, s = gm & 2047;
          const int h = g >> 6, d = g & 63;
          ((u16*)out)[(size_t)which * 8388608 + ((((size_t)((b << 4) + h) << 11) + s) << 6) + d] = f2bf(v);
        } else if constexpr (EPI == 1) {
          ((float*)out)[(size_t)gm * N + gn] = v + add[(size_t)gm * N + gn];
        } else {
          ((u16*)out)[(size_t)gm * N + gn] = f2bf(0.5f * v * (1.f + erff(v * 0.70710678118f)));
        }
      }
    }
  }
}

// ---------------- windowed attention (unchanged from round 0, passing)
template<int NJ>  // NJ = W/16 (24 or 32)
__device__ void attn_core(const u16* __restrict__ Qp, const u16* __restrict__ Kp,
    u16* __restrict__ ctx, char* vtb, char* plb,
    int start, int widx, int phase, int bh)
{
  const int tid = threadIdx.x, wave = tid >> 6, lane = tid & 63;
  const int lcol = lane & 15, lrow4 = lane >> 4;
  const float scale = 0.125f;  // 64^-0.5
  const int b = bh >> 4, h = bh & 15;

  for (int qt = wave; qt < NJ; qt += 4) {
    const int q0 = qt * 16;
    const bf16x8 aq0 = *(const bf16x8*)(Qp + (q0 + lcol) * 64 + lrow4 * 8);
    const bf16x8 aq1 = *(const bf16x8*)(Qp + (q0 + lcol) * 64 + 32 + lrow4 * 8);
    f32x4 acc[NJ] = {};
    #pragma unroll
    for (int j = 0; j < NJ; ++j) {
      bf16x8 k0 = *(const bf16x8*)(Kp + (j*16 + lcol) * 64 + lrow4 * 8);
      bf16x8 k1 = *(const bf16x8*)(Kp + (j*16 + lcol) * 64 + 32 + lrow4 * 8);
      acc[j] = __builtin_amdgcn_mfma_f32_16x16x32_bf16(aq0, k0, acc[j], 0, 0, 0);
      acc[j] = __builtin_amdgcn_mfma_f32_16x16x32_bf16(aq1, k1, acc[j], 0, 0, 0);
    }
    float rs[4];
    #pragma unroll
    for (int r = 0; r < 4; ++r) {
      float mx = -3.0e38f;
      #pragma unroll
      for (int j = 0; j < NJ; ++j) mx = fmaxf(mx, acc[j][r]);
      mx = fmaxf(mx, __shfl_xor(mx, 1, 64));
      mx = fmaxf(mx, __shfl_xor(mx, 2, 64));
      mx = fmaxf(mx, __shfl_xor(mx, 4, 64));
      mx = fmaxf(mx, __shfl_xor(mx, 8, 64));
      float sum = 0.f;
      const int prow = wave * 16 + lrow4 * 4 + r;
      #pragma unroll
      for (int j = 0; j < NJ; ++j) {
        float e = __expf((acc[j][r] - mx) * scale);
        sum += e;
        *(u16*)(plb + swz(prow, (j*16 + lcol) * 2)) = f2bf(e);
      }
      sum += __shfl_xor(sum, 1, 64);
      sum += __shfl_xor(sum, 2, 64);
      sum += __shfl_xor(sum, 4, 64);
      sum += __shfl_xor(sum, 8, 64);
      rs[r] = 1.f / sum;
    }
    f32x4 o[4] = {};
    #pragma unroll
    for (int kk = 0; kk < NJ / 2; ++kk) {
      bf16x8 pa = *(const bf16x8*)(plb + swz(wave*16 + lcol, (kk*32 + lrow4*8) * 2));
      #pragma unroll
      for (int d = 0; d < 4; ++d) {
        bf16x8 pb = *(const bf16x8*)(vtb + swz(d*16 + lcol, (kk*32 + lrow4*8) * 2));
        o[d] = __builtin_amdgcn_mfma_f32_16x16x32_bf16(pa, pb, o[d], 0, 0, 0);
      }
    }
    #pragma unroll
    for (int r = 0; r < 4; ++r) {
      int p = start + q0 + lrow4 * 4 + r;
      int rel = p - (widx * 256 - 128);
      float wgt = (rel < 256) ? ((widx == 0) ? 1.f : (float)rel * (1.f / 255.f))
                              : ((widx == 7) ? 1.f : (1.f - (float)(rel - 256) * (1.f / 255.f)));
      float rw = rs[r] * wgt;
      size_t base = (((size_t)(b << 11) + (size_t)p) << 10) + (h << 6);
      #pragma unroll
      for (int d = 0; d < 4; ++d) {
        size_t idx = base + d * 16 + lcol;
        float val = o[d][r] * rw;
        if (phase == 0)        ctx[idx] = f2bf(val);
        else if (p >= 1920)    ctx[idx] = f2bf(val);
        else                   ctx[idx] = f2bf(bf2f(ctx[idx]) + val);
      }
    }
  }
}

__global__ __launch_bounds__(256, 1) void attn_kernel(const u16* __restrict__ qg, const u16* __restrict__ kg,
    const u16* __restrict__ vg, u16* __restrict__ ctx, int phase){
  __shared__ u16 Vt[64 * 512];
  __shared__ u16 Pl[64 * 512];
  int widx = (((int)blockIdx.x >> 6) << 1) + phase;
  int bh = blockIdx.x & 63;
  int i0 = widx << 8;
  int start = i0 - 128; if (start < 0) start = 0;
  int end = i0 + 384;   if (end > 2048) end = 2048;
  int W = end - start;
  const u16* Qp = qg + (((size_t)bh << 11) + start) * 64;
  const u16* Kp = kg + (((size_t)bh << 11) + start) * 64;
  const u16* Vp = vg + (((size_t)bh << 11) + start) * 64;
  char* vtb = (char*)Vt;
  char* plb = (char*)Pl;
  for (int c = threadIdx.x; c < W * 8; c += 256) {
    int key = c >> 3, d0 = (c & 7) << 3;
    u16x8 vv = *(const u16x8*)(Vp + key * 64 + d0);
    #pragma unroll
    for (int z = 0; z < 8; ++z)
      *(u16*)(vtb + swz(d0 + z, key * 2)) = vv[z];
  }
  __syncthreads();
  if (W == 512) attn_core<32>(Qp, Kp, ctx, vtb, plb, start, widx, phase, bh);
  else          attn_core<24>(Qp, Kp, ctx, vtb, plb, start, widx, phase, bh);
}

// ---------------- host
extern "C" void kernel_launch(void* const* d_in, const int* in_sizes, int n_in,
                              void* d_out, int out_size, void* d_ws, size_t ws_size,
                              hipStream_t stream) {
  const float* hidden = (const float*)d_in[0];
  const float* ln1_g  = (const float*)d_in[1];
  const float* ln1_b  = (const float*)d_in[2];
  const float* wq     = (const float*)d_in[3];
  const float* bq     = (const float*)d_in[4];
  const float* wk     = (const float*)d_in[5];
  const float* bk     = (const float*)d_in[6];
  const float* wv     = (const float*)d_in[7];
  const float* bv     = (const float*)d_in[8];
  const float* wproj  = (const float*)d_in[9];
  const float* bproj  = (const float*)d_in[10];
  const float* ln2_g  = (const float*)d_in[11];
  const float* ln2_b  = (const float*)d_in[12];
  const float* w1     = (const float*)d_in[13];
  const float* b1     = (const float*)d_in[14];
  const float* w2     = (const float*)d_in[15];
  const float* b2     = (const float*)d_in[16];

  char* ws = (char*)d_ws;
  u16* xb    = (u16*)(ws + 0);            // 16 MiB (LN1/LN2 out)
  u16* wqkvT = (u16*)(ws + 16777216);     // 6 MiB [3072][1024]
  u16* wpT   = (u16*)(ws + 23068672);     // 2 MiB
  u16* w1T   = (u16*)(ws + 25165824);     // 8 MiB
  u16* w2T   = (u16*)(ws + 33554432);     // 8 MiB
  u16* qb    = (u16*)(ws + 41943040);     // q,k,v contiguous: 3 x 16 MiB
  u16* kb    = (u16*)(ws + 58720256);
  u16* vb    = (u16*)(ws + 75497472);
  u16* ctx   = (u16*)(ws + 92274688);     // 16 MiB
  float* bqkv = (float*)(ws + 92274688);  // aliases ctx start (dead before attn)
  float* res2 = (float*)(ws + 109051904); // 32 MiB f32
  u16* mid   = (u16*)(ws + 41943040);     // 64 MiB, reuses qb..ctx

  dim3 tb(32, 8);
  transpose_cvt<<<dim3(32, 32), tb, 0, stream>>>(wq, wqkvT, 1024, 1024);
  transpose_cvt<<<dim3(32, 32), tb, 0, stream>>>(wk, wqkvT + 1048576, 1024, 1024);
  transpose_cvt<<<dim3(32, 32), tb, 0, stream>>>(wv, wqkvT + 2097152, 1024, 1024);
  transpose_cvt<<<dim3(32, 32), tb, 0, stream>>>(wproj, wpT, 1024, 1024);
  transpose_cvt<<<dim3(128, 32), tb, 0, stream>>>(w1, w1T, 1024, 4096);
  transpose_cvt<<<dim3(32, 128), tb, 0, stream>>>(w2, w2T, 4096, 1024);
  concat3<<<12, 256, 0, stream>>>(bq, bk, bv, bqkv);

  ln_kernel<<<8192, 256, 0, stream>>>(hidden, ln1_g, ln1_b, xb);

  gemm8<0><<<384, 512, 0, stream>>>(xb, wqkvT, bqkv, nullptr, qb, 8192, 3072, 1024);

  attn_kernel<<<256, 256, 0, stream>>>(qb, kb, vb, ctx, 0);
  attn_kernel<<<256, 256, 0, stream>>>(qb, kb, vb, ctx, 1);

  gemm8<1><<<128, 512, 0, stream>>>(ctx, wpT, bproj, hidden, res2, 8192, 1024, 1024);

  ln_kernel<<<8192, 256, 0, stream>>>(res2, ln2_g, ln2_b, xb);

  gemm8<2><<<512, 512, 0, stream>>>(xb, w1T, b1, nullptr, mid, 8192, 4096, 1024);
  gemm8<1><<<128, 512, 0, stream>>>(mid, w2T, b2, res2, (float*)d_out, 8192, 1024, 4096);
}

// Round 4
// 568.808 us; speedup vs baseline: 1.0962x; 1.0962x over previous
//
#include <hip/hip_runtime.h>
#include <math.h>

typedef unsigned short u16;
typedef __attribute__((ext_vector_type(8))) short bf16x8;
typedef __attribute__((ext_vector_type(8))) unsigned short u16x8;
typedef __attribute__((ext_vector_type(4))) float f32x4;

__device__ __forceinline__ u16 f2bf(float f){
  union { float f; unsigned u; } c; c.f = f;
  unsigned u = c.u;
  return (u16)((u + 0x7fffu + ((u >> 16) & 1u)) >> 16);
}
__device__ __forceinline__ float bf2f(u16 h){
  union { unsigned u; float f; } c; c.u = ((unsigned)h) << 16;
  return c.f;
}
__device__ __forceinline__ void gload_lds16(const void* g, void* l){
  __builtin_amdgcn_global_load_lds((const __attribute__((address_space(1))) void*)g,
                                   (__attribute__((address_space(3))) void*)l, 16, 0, 0);
}
// XOR swizzle within a 1024B LDS row (attention kernels)
__device__ __forceinline__ int swz(int row, int bc){
  return (row << 10) + (bc ^ ((row & 7) << 4));
}

// ---------------- weight transpose + f32->bf16 : in [K][N] f32 -> out [N][K] bf16
__global__ void transpose_cvt(const float* __restrict__ in, u16* __restrict__ out, int K, int N){
  __shared__ float tile[32][33];
  int n0 = blockIdx.x << 5, k0 = blockIdx.y << 5;
  int tx = threadIdx.x, ty = threadIdx.y;
  #pragma unroll
  for (int r = 0; r < 32; r += 8)
    tile[ty + r][tx] = in[(size_t)(k0 + ty + r) * N + n0 + tx];
  __syncthreads();
  #pragma unroll
  for (int r = 0; r < 32; r += 8)
    out[(size_t)(n0 + ty + r) * K + k0 + tx] = f2bf(tile[tx][ty + r]);
}

__global__ void concat3(const float* __restrict__ a, const float* __restrict__ b,
                        const float* __restrict__ c, float* __restrict__ o){
  int i = blockIdx.x * 256 + threadIdx.x;
  o[i] = i < 1024 ? a[i] : (i < 2048 ? b[i - 1024] : c[i - 2048]);
}

// ---------------- layernorm: f32 [rows][1024] -> bf16 [rows][1024]
__device__ __forceinline__ float blockReduce(float v, float* ws){
  #pragma unroll
  for (int m = 1; m < 64; m <<= 1) v += __shfl_xor(v, m, 64);
  int w = threadIdx.x >> 6;
  __syncthreads();
  if ((threadIdx.x & 63) == 0) ws[w] = v;
  __syncthreads();
  return ws[0] + ws[1] + ws[2] + ws[3];
}

struct U16x4 { u16 x, y, z, w; };

__global__ __launch_bounds__(256) void ln_kernel(const float* __restrict__ in, const float* __restrict__ g,
    const float* __restrict__ be, u16* __restrict__ out){
  __shared__ float ws[4];
  int row = blockIdx.x;
  const float4 v = ((const float4*)(in + ((size_t)row << 10)))[threadIdx.x];
  float s = v.x + v.y + v.z + v.w;
  s = blockReduce(s, ws);
  float mean = s * (1.f / 1024.f);
  float dx = v.x - mean, dy = v.y - mean, dz = v.z - mean, dw = v.w - mean;
  float s2 = dx*dx + dy*dy + dz*dz + dw*dw;
  s2 = blockReduce(s2, ws);
  float rstd = rsqrtf(s2 * (1.f / 1024.f) + 1e-5f);
  float4 gv = ((const float4*)g)[threadIdx.x];
  float4 bv = ((const float4*)be)[threadIdx.x];
  U16x4 ov;
  ov.x = f2bf(dx * rstd * gv.x + bv.x);
  ov.y = f2bf(dy * rstd * gv.y + bv.y);
  ov.z = f2bf(dz * rstd * gv.z + bv.z);
  ov.w = f2bf(dw * rstd * gv.w + bv.w);
  ((U16x4*)(out + ((size_t)row << 10)))[threadIdx.x] = ov;
}

// ---------------- 256x256 8-phase bf16 GEMM, register-pipelined subtile reads.
// A [M][K], Bt [N][K]. BK=64, 8 waves (2M x 4N), per-wave 128x64.
// Each phase: issue ONE subtile ds-read (af[8] or bv[4]) for a LATER phase,
// issue 1 half-tile stage, then MFMA from regs loaded in earlier phases.
// Stage order/iter: nb0.B0,nb0.A0,nb0.B1,nb0.A1,nb1.A0,nb1.B0,nb1.B1,nb1.A1
// (5-phase lead each). Waits vmcnt(8) at ends of p2/p4/p6/p8 retire exactly
// the 5-phase-old pair. Reg buffers af[2]/bv[2]: consume (A0B0)(A0B1)(A1B0)
// (A1B1) x2; each overwrite >=1 phase after last use. All LDS WAR gaps >=2
// phases with barriers between.

#define BAR() asm volatile("s_barrier" ::: "memory")

template<int CQM, int CQN, int RK, int RD, int RLB, int RQ, int WAIT, typename F>
__device__ __forceinline__ void phase(const char* lds, const int (&aoff)[2], const int (&boff)[2],
    bf16x8 (&af)[2][4][2], bf16x8 (&bv)[2][2][2], f32x4 (&acc)[8][4], F&& stg){
  if constexpr (RK == 0) {
    const char* src = lds + RLB*65536 + RQ*16384;
    #pragma unroll
    for (int fi = 0; fi < 4; ++fi)
      #pragma unroll
      for (int ks = 0; ks < 2; ++ks)
        af[RD][fi][ks] = *(const bf16x8*)(src + fi*2048 + aoff[ks]);
  } else {
    const char* src = lds + RLB*65536 + 32768 + RQ*16384;
    #pragma unroll
    for (int fj = 0; fj < 2; ++fj)
      #pragma unroll
      for (int ks = 0; ks < 2; ++ks)
        bv[RD][fj][ks] = *(const bf16x8*)(src + fj*2048 + boff[ks]);
  }
  stg();
  __builtin_amdgcn_sched_barrier(0);  // reads+stage stay above the MFMA cluster
  __builtin_amdgcn_s_setprio(1);
  #pragma unroll
  for (int fi = 0; fi < 4; ++fi)
    #pragma unroll
    for (int fj = 0; fj < 2; ++fj){
      acc[CQM*4+fi][CQN*2+fj] = __builtin_amdgcn_mfma_f32_16x16x32_bf16(af[CQM][fi][0], bv[CQN][fj][0], acc[CQM*4+fi][CQN*2+fj], 0, 0, 0);
      acc[CQM*4+fi][CQN*2+fj] = __builtin_amdgcn_mfma_f32_16x16x32_bf16(af[CQM][fi][1], bv[CQN][fj][1], acc[CQM*4+fi][CQN*2+fj], 0, 0, 0);
    }
  __builtin_amdgcn_s_setprio(0);
  if constexpr (WAIT >= 0)
    asm volatile("s_waitcnt vmcnt(%0)" :: "n"(WAIT) : "memory");
  BAR();
}

// EPI 0: bf16 scatter to q/k/v [3][B*NH, S, HD] (+bias)
// EPI 1: f32 = acc + bias + add
// EPI 2: bf16 = gelu(acc + bias)
template<int EPI>
__global__ __launch_bounds__(512, 2) void gemm8(
    const u16* __restrict__ A, const u16* __restrict__ Bt,
    const float* __restrict__ bias, const float* __restrict__ add,
    void* __restrict__ out, int M, int N, int K)
{
  __shared__ char lds[147456];
  const int NT = K >> 6;
  const int NI = NT >> 1;
  const int nbx = N >> 8;
  // bijective XCD swizzle (m204)
  const int nwg = gridDim.x, orig = blockIdx.x;
  const int q = nwg >> 3, r = nwg & 7, x = orig & 7;
  const int wg = (x < r ? x * (q + 1) : r * (q + 1) + (x - r) * q) + (orig >> 3);
  const int bx = wg % nbx, by = wg / nbx;
  const int m0 = by << 8, n0 = bx << 8;

  const int tid = threadIdx.x, wave = tid >> 6, lane = tid & 63;
  const int wr = (wave >> 2) & 1, wc = wave & 3;
  const int lcol = lane & 15, lrow4 = lane >> 4;

  int aoff[2], boff[2];
  #pragma unroll
  for (int ks = 0; ks < 2; ++ks){
    const int chunk = (ks*4 + lrow4) ^ (lane & 7);
    aoff[ks] = (wr*64 + lcol)*128 + chunk*16;
    boff[ks] = (wc*32 + lcol)*128 + chunk*16;
  }

  // STAGE half h of K-tile tt. Pre-swizzled SOURCE + linear LDS dest
  // (rule #21): LDS chunk c holds global chunk c ^ (row&7). Out-of-range
  // tiles go to the dump region (keeps vmcnt exact in the tail).
  auto STAGE = [&](const u16* Mat, int rbase, int isB, int h, int tt){
    const int rb = (tt < NT) ? ((tt & 1) * 65536 + isB * 32768 + h * 16384) : 131072;
    const int tc = (tt < NT) ? tt : NT - 1;
    #pragma unroll
    for (int s = 0; s < 2; ++s){
      const int o = (tid + s*512) << 4;
      const int row = o >> 7;
      const int c = (o >> 4) & 7;
      const char* src = (const char*)(Mat + (size_t)(rbase + h*128 + row) * K + (size_t)tc * 64)
                        + ((c ^ (row & 7)) << 4);
      gload_lds16(src, (char*)lds + rb + o);
    }
  };

  f32x4 acc[8][4] = {};
  bf16x8 af[2][4][2], bv[2][2][2];

  // prologue: queue order b0.A0,b0.B0,b0.A1,b0.B1, b1.A0,b1.B0,b1.B1,b1.A1
  STAGE(A,  m0, 0, 0, 0);
  STAGE(Bt, n0, 1, 0, 0);
  STAGE(A,  m0, 0, 1, 0);
  STAGE(Bt, n0, 1, 1, 0);
  STAGE(A,  m0, 0, 0, 1);
  STAGE(Bt, n0, 1, 0, 1);
  STAGE(Bt, n0, 1, 1, 1);
  STAGE(A,  m0, 0, 1, 1);
  asm volatile("s_waitcnt vmcnt(8)" ::: "memory");  // b0 fully landed
  BAR();
  // preload regs for p1: af[0] <- (buf0,M0), bv[0] <- (buf0,N0)
  #pragma unroll
  for (int fi = 0; fi < 4; ++fi)
    #pragma unroll
    for (int ks = 0; ks < 2; ++ks)
      af[0][fi][ks] = *(const bf16x8*)(lds + fi*2048 + aoff[ks]);
  #pragma unroll
  for (int fj = 0; fj < 2; ++fj)
    #pragma unroll
    for (int ks = 0; ks < 2; ++ks)
      bv[0][fj][ks] = *(const bf16x8*)(lds + 32768 + fj*2048 + boff[ks]);

  for (int i = 0; i < NI; ++i) {
    const int T = 2*i;
    //    CQM CQN RK RD RLB RQ  W
    phase<0,  0,  1, 1, 0,  1, -1>(lds, aoff, boff, af, bv, acc, [&]{ STAGE(Bt, n0, 1, 0, T+2); });
    phase<0,  1,  0, 1, 0,  1,  8>(lds, aoff, boff, af, bv, acc, [&]{ STAGE(A,  m0, 0, 0, T+2); });
    phase<1,  0,  0, 0, 1,  0, -1>(lds, aoff, boff, af, bv, acc, [&]{ STAGE(Bt, n0, 1, 1, T+2); });
    phase<1,  1,  1, 0, 1,  0,  8>(lds, aoff, boff, af, bv, acc, [&]{ STAGE(A,  m0, 0, 1, T+2); });
    phase<0,  0,  1, 1, 1,  1, -1>(lds, aoff, boff, af, bv, acc, [&]{ STAGE(A,  m0, 0, 0, T+3); });
    phase<0,  1,  0, 1, 1,  1,  8>(lds, aoff, boff, af, bv, acc, [&]{ STAGE(Bt, n0, 1, 0, T+3); });
    phase<1,  0,  0, 0, 0,  0, -1>(lds, aoff, boff, af, bv, acc, [&]{ STAGE(Bt, n0, 1, 1, T+3); });
    phase<1,  1,  1, 0, 0,  0,  8>(lds, aoff, boff, af, bv, acc, [&]{ STAGE(A,  m0, 0, 1, T+3); });
  }

  // launder epilogue pointers so their loads can't be hoisted into the K-loop
  { size_t bp = (size_t)bias, ap = (size_t)add;
    asm volatile("" : "+v"(bp), "+v"(ap));
    bias = (const float*)bp; add = (const float*)ap; }

  #pragma unroll
  for (int mi = 0; mi < 8; ++mi) {
    const int gmb = m0 + (mi>>2)*128 + wr*64 + (mi&3)*16 + lrow4*4;
    #pragma unroll
    for (int ni = 0; ni < 4; ++ni) {
      const int gn = n0 + (ni>>1)*128 + wc*32 + (ni&1)*16 + lcol;
      const float bs = bias[gn];
      #pragma unroll
      for (int rr = 0; rr < 4; ++rr) {
        const int gm = gmb + rr;
        float v = acc[mi][ni][rr] + bs;
        if constexpr (EPI == 0) {
          const int which = gn >> 10, g = gn & 1023;
          const int b = gm >> 11, s = gm & 2047;
          const int h = g >> 6, d = g & 63;
          ((u16*)out)[(size_t)which * 8388608 + ((((size_t)((b << 4) + h) << 11) + s) << 6) + d] = f2bf(v);
        } else if constexpr (EPI == 1) {
          ((float*)out)[(size_t)gm * N + gn] = v + add[(size_t)gm * N + gn];
        } else {
          ((u16*)out)[(size_t)gm * N + gn] = f2bf(0.5f * v * (1.f + erff(v * 0.70710678118f)));
        }
      }
    }
  }
}

// ---------------- windowed attention (unchanged, passing)
template<int NJ>  // NJ = W/16 (24 or 32)
__device__ void attn_core(const u16* __restrict__ Qp, const u16* __restrict__ Kp,
    u16* __restrict__ ctx, char* vtb, char* plb,
    int start, int widx, int phase_, int bh)
{
  const int tid = threadIdx.x, wave = tid >> 6, lane = tid & 63;
  const int lcol = lane & 15, lrow4 = lane >> 4;
  const float scale = 0.125f;  // 64^-0.5
  const int b = bh >> 4, h = bh & 15;

  for (int qt = wave; qt < NJ; qt += 4) {
    const int q0 = qt * 16;
    const bf16x8 aq0 = *(const bf16x8*)(Qp + (q0 + lcol) * 64 + lrow4 * 8);
    const bf16x8 aq1 = *(const bf16x8*)(Qp + (q0 + lcol) * 64 + 32 + lrow4 * 8);
    f32x4 acc[NJ] = {};
    #pragma unroll
    for (int j = 0; j < NJ; ++j) {
      bf16x8 k0 = *(const bf16x8*)(Kp + (j*16 + lcol) * 64 + lrow4 * 8);
      bf16x8 k1 = *(const bf16x8*)(Kp + (j*16 + lcol) * 64 + 32 + lrow4 * 8);
      acc[j] = __builtin_amdgcn_mfma_f32_16x16x32_bf16(aq0, k0, acc[j], 0, 0, 0);
      acc[j] = __builtin_amdgcn_mfma_f32_16x16x32_bf16(aq1, k1, acc[j], 0, 0, 0);
    }
    float rs[4];
    #pragma unroll
    for (int r = 0; r < 4; ++r) {
      float mx = -3.0e38f;
      #pragma unroll
      for (int j = 0; j < NJ; ++j) mx = fmaxf(mx, acc[j][r]);
      mx = fmaxf(mx, __shfl_xor(mx, 1, 64));
      mx = fmaxf(mx, __shfl_xor(mx, 2, 64));
      mx = fmaxf(mx, __shfl_xor(mx, 4, 64));
      mx = fmaxf(mx, __shfl_xor(mx, 8, 64));
      float sum = 0.f;
      const int prow = wave * 16 + lrow4 * 4 + r;
      #pragma unroll
      for (int j = 0; j < NJ; ++j) {
        float e = __expf((acc[j][r] - mx) * scale);
        sum += e;
        *(u16*)(plb + swz(prow, (j*16 + lcol) * 2)) = f2bf(e);
      }
      sum += __shfl_xor(sum, 1, 64);
      sum += __shfl_xor(sum, 2, 64);
      sum += __shfl_xor(sum, 4, 64);
      sum += __shfl_xor(sum, 8, 64);
      rs[r] = 1.f / sum;
    }
    f32x4 o[4] = {};
    #pragma unroll
    for (int kk = 0; kk < NJ / 2; ++kk) {
      bf16x8 pa = *(const bf16x8*)(plb + swz(wave*16 + lcol, (kk*32 + lrow4*8) * 2));
      #pragma unroll
      for (int d = 0; d < 4; ++d) {
        bf16x8 pb = *(const bf16x8*)(vtb + swz(d*16 + lcol, (kk*32 + lrow4*8) * 2));
        o[d] = __builtin_amdgcn_mfma_f32_16x16x32_bf16(pa, pb, o[d], 0, 0, 0);
      }
    }
    #pragma unroll
    for (int r = 0; r < 4; ++r) {
      int p = start + q0 + lrow4 * 4 + r;
      int rel = p - (widx * 256 - 128);
      float wgt = (rel < 256) ? ((widx == 0) ? 1.f : (float)rel * (1.f / 255.f))
                              : ((widx == 7) ? 1.f : (1.f - (float)(rel - 256) * (1.f / 255.f)));
      float rw = rs[r] * wgt;
      size_t base = (((size_t)(b << 11) + (size_t)p) << 10) + (h << 6);
      #pragma unroll
      for (int d = 0; d < 4; ++d) {
        size_t idx = base + d * 16 + lcol;
        float val = o[d][r] * rw;
        if (phase_ == 0)       ctx[idx] = f2bf(val);
        else if (p >= 1920)    ctx[idx] = f2bf(val);
        else                   ctx[idx] = f2bf(bf2f(ctx[idx]) + val);
      }
    }
  }
}

__global__ __launch_bounds__(256, 1) void attn_kernel(const u16* __restrict__ qg, const u16* __restrict__ kg,
    const u16* __restrict__ vg, u16* __restrict__ ctx, int phase_){
  __shared__ u16 Vt[64 * 512];
  __shared__ u16 Pl[64 * 512];
  int widx = (((int)blockIdx.x >> 6) << 1) + phase_;
  int bh = blockIdx.x & 63;
  int i0 = widx << 8;
  int start = i0 - 128; if (start < 0) start = 0;
  int end = i0 + 384;   if (end > 2048) end = 2048;
  int W = end - start;
  const u16* Qp = qg + (((size_t)bh << 11) + start) * 64;
  const u16* Kp = kg + (((size_t)bh << 11) + start) * 64;
  const u16* Vp = vg + (((size_t)bh << 11) + start) * 64;
  char* vtb = (char*)Vt;
  char* plb = (char*)Pl;
  for (int c = threadIdx.x; c < W * 8; c += 256) {
    int key = c >> 3, d0 = (c & 7) << 3;
    u16x8 vv = *(const u16x8*)(Vp + key * 64 + d0);
    #pragma unroll
    for (int z = 0; z < 8; ++z)
      *(u16*)(vtb + swz(d0 + z, key * 2)) = vv[z];
  }
  __syncthreads();
  if (W == 512) attn_core<32>(Qp, Kp, ctx, vtb, plb, start, widx, phase_, bh);
  else          attn_core<24>(Qp, Kp, ctx, vtb, plb, start, widx, phase_, bh);
}

// ---------------- host
extern "C" void kernel_launch(void* const* d_in, const int* in_sizes, int n_in,
                              void* d_out, int out_size, void* d_ws, size_t ws_size,
                              hipStream_t stream) {
  const float* hidden = (const float*)d_in[0];
  const float* ln1_g  = (const float*)d_in[1];
  const float* ln1_b  = (const float*)d_in[2];
  const float* wq     = (const float*)d_in[3];
  const float* bq     = (const float*)d_in[4];
  const float* wk     = (const float*)d_in[5];
  const float* bk     = (const float*)d_in[6];
  const float* wv     = (const float*)d_in[7];
  const float* bv     = (const float*)d_in[8];
  const float* wproj  = (const float*)d_in[9];
  const float* bproj  = (const float*)d_in[10];
  const float* ln2_g  = (const float*)d_in[11];
  const float* ln2_b  = (const float*)d_in[12];
  const float* w1     = (const float*)d_in[13];
  const float* b1     = (const float*)d_in[14];
  const float* w2     = (const float*)d_in[15];
  const float* b2     = (const float*)d_in[16];

  char* ws = (char*)d_ws;
  u16* xb    = (u16*)(ws + 0);            // 16 MiB (LN1/LN2 out)
  u16* wqkvT = (u16*)(ws + 16777216);     // 6 MiB [3072][1024]
  u16* wpT   = (u16*)(ws + 23068672);     // 2 MiB
  u16* w1T   = (u16*)(ws + 25165824);     // 8 MiB
  u16* w2T   = (u16*)(ws + 33554432);     // 8 MiB
  u16* qb    = (u16*)(ws + 41943040);     // q,k,v contiguous: 3 x 16 MiB
  u16* kb    = (u16*)(ws + 58720256);
  u16* vb    = (u16*)(ws + 75497472);
  u16* ctx   = (u16*)(ws + 92274688);     // 16 MiB
  float* bqkv = (float*)(ws + 92274688);  // aliases ctx start (dead before attn)
  float* res2 = (float*)(ws + 109051904); // 32 MiB f32
  u16* mid   = (u16*)(ws + 41943040);     // 64 MiB, reuses qb..ctx

  dim3 tb(32, 8);
  transpose_cvt<<<dim3(32, 32), tb, 0, stream>>>(wq, wqkvT, 1024, 1024);
  transpose_cvt<<<dim3(32, 32), tb, 0, stream>>>(wk, wqkvT + 1048576, 1024, 1024);
  transpose_cvt<<<dim3(32, 32), tb, 0, stream>>>(wv, wqkvT + 2097152, 1024, 1024);
  transpose_cvt<<<dim3(32, 32), tb, 0, stream>>>(wproj, wpT, 1024, 1024);
  transpose_cvt<<<dim3(128, 32), tb, 0, stream>>>(w1, w1T, 1024, 4096);
  transpose_cvt<<<dim3(32, 128), tb, 0, stream>>>(w2, w2T, 4096, 1024);
  concat3<<<12, 256, 0, stream>>>(bq, bk, bv, bqkv);

  ln_kernel<<<8192, 256, 0, stream>>>(hidden, ln1_g, ln1_b, xb);

  gemm8<0><<<384, 512, 0, stream>>>(xb, wqkvT, bqkv, nullptr, qb, 8192, 3072, 1024);

  attn_kernel<<<256, 256, 0, stream>>>(qb, kb, vb, ctx, 0);
  attn_kernel<<<256, 256, 0, stream>>>(qb, kb, vb, ctx, 1);

  gemm8<1><<<128, 512, 0, stream>>>(ctx, wpT, bproj, hidden, res2, 8192, 1024, 1024);

  ln_kernel<<<8192, 256, 0, stream>>>(res2, ln2_g, ln2_b, xb);

  gemm8<2><<<512, 512, 0, stream>>>(xb, w1T, b1, nullptr, mid, 8192, 4096, 1024);
  gemm8<1><<<128, 512, 0, stream>>>(mid, w2T, b2, res2, (float*)d_out, 8192, 1024, 4096);
}

// Round 5
// 518.393 us; speedup vs baseline: 1.2028x; 1.0973x over previous
//
#include <hip/hip_runtime.h>
#include <math.h>

typedef unsigned short u16;
typedef __attribute__((ext_vector_type(8))) short bf16x8;
typedef __attribute__((ext_vector_type(8))) unsigned short u16x8;
typedef __attribute__((ext_vector_type(4))) float f32x4;

__device__ __forceinline__ u16 f2bf(float f){
  union { float f; unsigned u; } c; c.f = f;
  unsigned u = c.u;
  return (u16)((u + 0x7fffu + ((u >> 16) & 1u)) >> 16);
}
__device__ __forceinline__ float bf2f(u16 h){
  union { unsigned u; float f; } c; c.u = ((unsigned)h) << 16;
  return c.f;
}
__device__ __forceinline__ void gload_lds16(const void* g, void* l){
  __builtin_amdgcn_global_load_lds((const __attribute__((address_space(1))) void*)g,
                                   (__attribute__((address_space(3))) void*)l, 16, 0, 0);
}
// XOR swizzle within a 1024B LDS row (attention kernels)
__device__ __forceinline__ int swz(int row, int bc){
  return (row << 10) + (bc ^ ((row & 7) << 4));
}

#define BAR() asm volatile("s_barrier" ::: "memory")

// ---------------- weight transpose + f32->bf16 : in [K][N] f32 -> out [N][K] bf16
__global__ void transpose_cvt(const float* __restrict__ in, u16* __restrict__ out, int K, int N){
  __shared__ float tile[32][33];
  int n0 = blockIdx.x << 5, k0 = blockIdx.y << 5;
  int tx = threadIdx.x, ty = threadIdx.y;
  #pragma unroll
  for (int r = 0; r < 32; r += 8)
    tile[ty + r][tx] = in[(size_t)(k0 + ty + r) * N + n0 + tx];
  __syncthreads();
  #pragma unroll
  for (int r = 0; r < 32; r += 8)
    out[(size_t)(n0 + ty + r) * K + k0 + tx] = f2bf(tile[tx][ty + r]);
}

__global__ void concat3(const float* __restrict__ a, const float* __restrict__ b,
                        const float* __restrict__ c, float* __restrict__ o){
  int i = blockIdx.x * 256 + threadIdx.x;
  o[i] = i < 1024 ? a[i] : (i < 2048 ? b[i - 1024] : c[i - 2048]);
}

// ---------------- layernorm: f32 [rows][1024] -> bf16 [rows][1024]
__device__ __forceinline__ float blockReduce(float v, float* ws){
  #pragma unroll
  for (int m = 1; m < 64; m <<= 1) v += __shfl_xor(v, m, 64);
  int w = threadIdx.x >> 6;
  __syncthreads();
  if ((threadIdx.x & 63) == 0) ws[w] = v;
  __syncthreads();
  return ws[0] + ws[1] + ws[2] + ws[3];
}

struct U16x4 { u16 x, y, z, w; };

__global__ __launch_bounds__(256) void ln_kernel(const float* __restrict__ in, const float* __restrict__ g,
    const float* __restrict__ be, u16* __restrict__ out){
  __shared__ float ws[4];
  int row = blockIdx.x;
  const float4 v = ((const float4*)(in + ((size_t)row << 10)))[threadIdx.x];
  float s = v.x + v.y + v.z + v.w;
  s = blockReduce(s, ws);
  float mean = s * (1.f / 1024.f);
  float dx = v.x - mean, dy = v.y - mean, dz = v.z - mean, dw = v.w - mean;
  float s2 = dx*dx + dy*dy + dz*dz + dw*dw;
  s2 = blockReduce(s2, ws);
  float rstd = rsqrtf(s2 * (1.f / 1024.f) + 1e-5f);
  float4 gv = ((const float4*)g)[threadIdx.x];
  float4 bv = ((const float4*)be)[threadIdx.x];
  U16x4 ov;
  ov.x = f2bf(dx * rstd * gv.x + bv.x);
  ov.y = f2bf(dy * rstd * gv.y + bv.y);
  ov.z = f2bf(dz * rstd * gv.z + bv.z);
  ov.w = f2bf(dw * rstd * gv.w + bv.w);
  ((U16x4*)(out + ((size_t)row << 10)))[threadIdx.x] = ov;
}

// ================= 256x256 8-phase bf16 GEMM, m201 phase shape =================
// A [M][K], Bt [N][K]. BK=64, 8 waves (2M x 4N), per-wave 128x64.
// Phase: {reads for THIS phase's MFMA; stage; barrier; lgkmcnt(0); MFMA; [vmcnt]; barrier}
// Quadrant order per K-tile: (0,0) (0,1) (1,1) (1,0). Single-buffered af/bv.
// Stage calendar (iter i, T=2i): p1 B0(T+1), p2 A0(T+2), p3 -, p4 B1(T+2),
//   p5 B0(T+2), p6 A1(T+2), p7 A0(T+3), p8 B1(T+3)+A1(T+3).
// Waits: vmcnt(4) end-p4 (retires thru p1 -> tile T+1 complete),
//        vmcnt(6) end-p8 (retires thru p6 -> tile T+2 complete).
// WAR: every stage >=1 barrier after its region's last ds_read (checked per slot).

template<int QM, int QN, int LB, int RDA, int WAIT, typename F>
__device__ __forceinline__ void ph256(const char* lds, const int (&aoff)[2], const int (&boff)[2],
    bf16x8 (&af)[4][2], bf16x8 (&bv)[2][2], f32x4 (&acc)[8][4], F&& stg){
  if constexpr (RDA) {
    const char* Ar = lds + LB*65536 + QM*16384;
    #pragma unroll
    for (int fi = 0; fi < 4; ++fi)
      #pragma unroll
      for (int ks = 0; ks < 2; ++ks)
        af[fi][ks] = *(const bf16x8*)(Ar + fi*2048 + aoff[ks]);
  }
  {
    const char* Br = lds + LB*65536 + 32768 + QN*16384;
    #pragma unroll
    for (int fj = 0; fj < 2; ++fj)
      #pragma unroll
      for (int ks = 0; ks < 2; ++ks)
        bv[fj][ks] = *(const bf16x8*)(Br + fj*2048 + boff[ks]);
  }
  stg();
  BAR();
  asm volatile("s_waitcnt lgkmcnt(0)" ::: "memory");
  __builtin_amdgcn_sched_barrier(0);
  __builtin_amdgcn_s_setprio(1);
  #pragma unroll
  for (int fi = 0; fi < 4; ++fi)
    #pragma unroll
    for (int fj = 0; fj < 2; ++fj){
      acc[QM*4+fi][QN*2+fj] = __builtin_amdgcn_mfma_f32_16x16x32_bf16(af[fi][0], bv[fj][0], acc[QM*4+fi][QN*2+fj], 0, 0, 0);
      acc[QM*4+fi][QN*2+fj] = __builtin_amdgcn_mfma_f32_16x16x32_bf16(af[fi][1], bv[fj][1], acc[QM*4+fi][QN*2+fj], 0, 0, 0);
    }
  __builtin_amdgcn_s_setprio(0);
  if constexpr (WAIT >= 0)
    asm volatile("s_waitcnt vmcnt(%0)" :: "n"(WAIT) : "memory");
  BAR();
}

// EPI 0: bf16 scatter to q/k/v [3][B*NH, S, HD] (+bias)
// EPI 2: bf16 = gelu(acc + bias)
template<int EPI>
__global__ __launch_bounds__(512, 2) void gemm8(
    const u16* __restrict__ A, const u16* __restrict__ Bt,
    const float* __restrict__ bias, const float* __restrict__ add,
    void* __restrict__ out, int M, int N, int K)
{
  __shared__ char lds[147456];
  const int NT = K >> 6;
  const int NI = NT >> 1;
  const int nbx = N >> 8;
  // bijective XCD swizzle (m204)
  const int nwg = gridDim.x, orig = blockIdx.x;
  const int q = nwg >> 3, r = nwg & 7, x = orig & 7;
  const int wg = (x < r ? x * (q + 1) : r * (q + 1) + (x - r) * q) + (orig >> 3);
  const int bx = wg % nbx, by = wg / nbx;
  const int m0 = by << 8, n0 = bx << 8;

  const int tid = threadIdx.x, wave = tid >> 6, lane = tid & 63;
  const int wr = (wave >> 2) & 1, wc = wave & 3;
  const int lcol = lane & 15, lrow4 = lane >> 4;

  int aoff[2], boff[2];
  #pragma unroll
  for (int ks = 0; ks < 2; ++ks){
    const int chunk = (ks*4 + lrow4) ^ (lane & 7);
    aoff[ks] = (wr*64 + lcol)*128 + chunk*16;
    boff[ks] = (wc*32 + lcol)*128 + chunk*16;
  }

  // STAGE half h of K-tile tt. Pre-swizzled SOURCE + linear LDS dest (rule #21):
  // LDS chunk c holds global chunk c ^ (row&7). tt >= NT -> dump region.
  auto STAGE = [&](const u16* Mat, int rbase, int isB, int h, int tt){
    const int rb = (tt < NT) ? ((tt & 1) * 65536 + isB * 32768 + h * 16384) : 131072;
    const int tc = (tt < NT) ? tt : NT - 1;
    #pragma unroll
    for (int s = 0; s < 2; ++s){
      const int o = (tid + s*512) << 4;
      const int row = o >> 7;
      const int c = (o >> 4) & 7;
      const char* src = (const char*)(Mat + (size_t)(rbase + h*128 + row) * K + (size_t)tc * 64)
                        + ((c ^ (row & 7)) << 4);
      gload_lds16(src, (char*)lds + rb + o);
    }
  };

  f32x4 acc[8][4] = {};
  bf16x8 af[4][2], bv[2][2];

  // prologue: A0(0),B0(0),A1(0),B1(0),A0(1),B1(1),A1(1); vmcnt(6) -> tile0 landed
  STAGE(A,  m0, 0, 0, 0);
  STAGE(Bt, n0, 1, 0, 0);
  STAGE(A,  m0, 0, 1, 0);
  STAGE(Bt, n0, 1, 1, 0);
  STAGE(A,  m0, 0, 0, 1);
  STAGE(Bt, n0, 1, 1, 1);
  STAGE(A,  m0, 0, 1, 1);
  asm volatile("s_waitcnt vmcnt(6)" ::: "memory");
  BAR();

  for (int i = 0; i < NI; ++i) {
    const int T = 2*i;
    //    QM QN LB RDA W
    ph256<0, 0, 0, 1, -1>(lds, aoff, boff, af, bv, acc, [&]{ STAGE(Bt, n0, 1, 0, T+1); });
    ph256<0, 1, 0, 0, -1>(lds, aoff, boff, af, bv, acc, [&]{ STAGE(A,  m0, 0, 0, T+2); });
    ph256<1, 1, 0, 1, -1>(lds, aoff, boff, af, bv, acc, [&]{});
    ph256<1, 0, 0, 0,  4>(lds, aoff, boff, af, bv, acc, [&]{ STAGE(Bt, n0, 1, 1, T+2); });
    ph256<0, 0, 1, 1, -1>(lds, aoff, boff, af, bv, acc, [&]{ STAGE(Bt, n0, 1, 0, T+2); });
    ph256<0, 1, 1, 0, -1>(lds, aoff, boff, af, bv, acc, [&]{ STAGE(A,  m0, 0, 1, T+2); });
    ph256<1, 1, 1, 1, -1>(lds, aoff, boff, af, bv, acc, [&]{ STAGE(A,  m0, 0, 0, T+3); });
    ph256<1, 0, 1, 0,  6>(lds, aoff, boff, af, bv, acc, [&]{ STAGE(Bt, n0, 1, 1, T+3); STAGE(A, m0, 0, 1, T+3); });
  }

  // launder epilogue pointers so their loads can't be hoisted into the K-loop
  { size_t bp = (size_t)bias, ap = (size_t)add;
    asm volatile("" : "+v"(bp), "+v"(ap));
    bias = (const float*)bp; add = (const float*)ap; }

  #pragma unroll
  for (int mi = 0; mi < 8; ++mi) {
    const int gmb = m0 + (mi>>2)*128 + wr*64 + (mi&3)*16 + lrow4*4;
    #pragma unroll
    for (int ni = 0; ni < 4; ++ni) {
      const int gn = n0 + (ni>>1)*128 + wc*32 + (ni&1)*16 + lcol;
      const float bs = bias[gn];
      #pragma unroll
      for (int rr = 0; rr < 4; ++rr) {
        const int gm = gmb + rr;
        float v = acc[mi][ni][rr] + bs;
        if constexpr (EPI == 0) {
          const int which = gn >> 10, g = gn & 1023;
          const int b = gm >> 11, s = gm & 2047;
          const int h = g >> 6, d = g & 63;
          ((u16*)out)[(size_t)which * 8388608 + ((((size_t)((b << 4) + h) << 11) + s) << 6) + d] = f2bf(v);
        } else {
          ((u16*)out)[(size_t)gm * N + gn] = f2bf(0.5f * v * (1.f + erff(v * 0.70710678118f)));
        }
      }
    }
  }
}

// ================= 128x256 4-phase bf16 GEMM (wide), same template shape ========
// Tile M=128, N=256, BK=64. 8 waves: wr=wave>>2 (2 M-halves), wc=wave&3.
// Per wave 64 rows x 64 cols (2 N-quadrants x 32). acc[4][4].
// LDS buf b at b*49152: A@0 (16KB), B0@16384, B1@32768; dump @98304. Total 106496.
// Phases/iter (T=2i): p1 read af(T)+bv(B0,T) stage B1(T+1); p2 read bv(B1,T)
//   stage A(T+2),B0(T+2), vmcnt(4); p3 read af(T+1)+bv(B0,T+1) stage B1(T+2);
//   p4 read bv(B1,T+1) stage A(T+3),B0(T+3), vmcnt(4).
// RAW: p2's vmcnt(4) retires thru p1's B1(T+1) -> tile T+1 ready for p3;
//      p4's vmcnt(4) retires thru p3's B1(T+2) -> tile T+2 ready for next p1.
// WAR: B1(T+1) over B1(T-1) last read prev-p4 OK; A/B0(T+2) over T last read p1 OK;
//      B1(T+2) over B1(T) last read p2 OK; A/B0(T+3) over T+1 last read p3 OK.

template<int QN, int LB, int RDA, int WAIT, typename F>
__device__ __forceinline__ void phW(const char* lds, const int (&aoff)[2], const int (&boff)[2],
    bf16x8 (&af)[4][2], bf16x8 (&bv)[2][2], f32x4 (&acc)[4][4], F&& stg){
  if constexpr (RDA) {
    const char* Ar = lds + LB*49152;
    #pragma unroll
    for (int fi = 0; fi < 4; ++fi)
      #pragma unroll
      for (int ks = 0; ks < 2; ++ks)
        af[fi][ks] = *(const bf16x8*)(Ar + fi*2048 + aoff[ks]);
  }
  {
    const char* Br = lds + LB*49152 + 16384 + QN*16384;
    #pragma unroll
    for (int fj = 0; fj < 2; ++fj)
      #pragma unroll
      for (int ks = 0; ks < 2; ++ks)
        bv[fj][ks] = *(const bf16x8*)(Br + fj*2048 + boff[ks]);
  }
  stg();
  BAR();
  asm volatile("s_waitcnt lgkmcnt(0)" ::: "memory");
  __builtin_amdgcn_sched_barrier(0);
  __builtin_amdgcn_s_setprio(1);
  #pragma unroll
  for (int fi = 0; fi < 4; ++fi)
    #pragma unroll
    for (int fj = 0; fj < 2; ++fj){
      acc[fi][QN*2+fj] = __builtin_amdgcn_mfma_f32_16x16x32_bf16(af[fi][0], bv[fj][0], acc[fi][QN*2+fj], 0, 0, 0);
      acc[fi][QN*2+fj] = __builtin_amdgcn_mfma_f32_16x16x32_bf16(af[fi][1], bv[fj][1], acc[fi][QN*2+fj], 0, 0, 0);
    }
  __builtin_amdgcn_s_setprio(0);
  if constexpr (WAIT >= 0)
    asm volatile("s_waitcnt vmcnt(%0)" :: "n"(WAIT) : "memory");
  BAR();
}

// out f32 = acc + bias + add   (proj+residual / ffn2+residual)
__global__ __launch_bounds__(512, 2) void gemmW(
    const u16* __restrict__ A, const u16* __restrict__ Bt,
    const float* __restrict__ bias, const float* __restrict__ add,
    float* __restrict__ out, int M, int N, int K)
{
  __shared__ char lds[106496];
  const int NT = K >> 6;
  const int NI = NT >> 1;
  const int nbx = N >> 8;
  const int nwg = gridDim.x, orig = blockIdx.x;
  const int q = nwg >> 3, r = nwg & 7, x = orig & 7;
  const int wg = (x < r ? x * (q + 1) : r * (q + 1) + (x - r) * q) + (orig >> 3);
  const int bx = wg % nbx, by = wg / nbx;
  const int m0 = by << 7, n0 = bx << 8;

  const int tid = threadIdx.x, wave = tid >> 6, lane = tid & 63;
  const int wr = wave >> 2, wc = wave & 3;
  const int lcol = lane & 15, lrow4 = lane >> 4;

  int aoff[2], boff[2];
  #pragma unroll
  for (int ks = 0; ks < 2; ++ks){
    const int chunk = (ks*4 + lrow4) ^ (lane & 7);
    aoff[ks] = (wr*64 + lcol)*128 + chunk*16;
    boff[ks] = (wc*32 + lcol)*128 + chunk*16;
  }

  // kind: 0=A (rows at m0), 1=B0 (rows at n0), 2=B1 (rows at n0+128)
  auto STAGE = [&](const u16* Mat, int rbase, int kind, int tt){
    const int rb = (tt < NT) ? ((tt & 1) * 49152 + kind * 16384) : 98304;
    const int tc = (tt < NT) ? tt : NT - 1;
    #pragma unroll
    for (int s = 0; s < 2; ++s){
      const int o = (tid + s*512) << 4;
      const int row = o >> 7;
      const int c = (o >> 4) & 7;
      const char* src = (const char*)(Mat + (size_t)(rbase + row) * K + (size_t)tc * 64)
                        + ((c ^ (row & 7)) << 4);
      gload_lds16(src, (char*)lds + rb + o);
    }
  };

  f32x4 acc[4][4] = {};
  bf16x8 af[4][2], bv[2][2];

  // prologue: A(0),B0(0),B1(0),A(1),B0(1); vmcnt(4) -> tile0 landed
  STAGE(A,  m0,       0, 0);
  STAGE(Bt, n0,       1, 0);
  STAGE(Bt, n0 + 128, 2, 0);
  STAGE(A,  m0,       0, 1);
  STAGE(Bt, n0,       1, 1);
  asm volatile("s_waitcnt vmcnt(4)" ::: "memory");
  BAR();

  for (int i = 0; i < NI; ++i) {
    const int T = 2*i;
    //  QN LB RDA W
    phW<0, 0, 1, -1>(lds, aoff, boff, af, bv, acc, [&]{ STAGE(Bt, n0 + 128, 2, T+1); });
    phW<1, 0, 0,  4>(lds, aoff, boff, af, bv, acc, [&]{ STAGE(A, m0, 0, T+2); STAGE(Bt, n0, 1, T+2); });
    phW<0, 1, 1, -1>(lds, aoff, boff, af, bv, acc, [&]{ STAGE(Bt, n0 + 128, 2, T+2); });
    phW<1, 1, 0,  4>(lds, aoff, boff, af, bv, acc, [&]{ STAGE(A, m0, 0, T+3); STAGE(Bt, n0, 1, T+3); });
  }

  { size_t bp = (size_t)bias, ap = (size_t)add;
    asm volatile("" : "+v"(bp), "+v"(ap));
    bias = (const float*)bp; add = (const float*)ap; }

  #pragma unroll
  for (int fi = 0; fi < 4; ++fi) {
    const int gmb = m0 + wr*64 + fi*16 + lrow4*4;
    #pragma unroll
    for (int j = 0; j < 4; ++j) {
      const int gn = n0 + (j>>1)*128 + wc*32 + (j&1)*16 + lcol;
      const float bs = bias[gn];
      #pragma unroll
      for (int rr = 0; rr < 4; ++rr) {
        const int gm = gmb + rr;
        out[(size_t)gm * N + gn] = acc[fi][j][rr] + bs + add[(size_t)gm * N + gn];
      }
    }
  }
}

// ---------------- windowed attention (unchanged, passing)
template<int NJ>  // NJ = W/16 (24 or 32)
__device__ void attn_core(const u16* __restrict__ Qp, const u16* __restrict__ Kp,
    u16* __restrict__ ctx, char* vtb, char* plb,
    int start, int widx, int phase_, int bh)
{
  const int tid = threadIdx.x, wave = tid >> 6, lane = tid & 63;
  const int lcol = lane & 15, lrow4 = lane >> 4;
  const float scale = 0.125f;  // 64^-0.5
  const int b = bh >> 4, h = bh & 15;

  for (int qt = wave; qt < NJ; qt += 4) {
    const int q0 = qt * 16;
    const bf16x8 aq0 = *(const bf16x8*)(Qp + (q0 + lcol) * 64 + lrow4 * 8);
    const bf16x8 aq1 = *(const bf16x8*)(Qp + (q0 + lcol) * 64 + 32 + lrow4 * 8);
    f32x4 acc[NJ] = {};
    #pragma unroll
    for (int j = 0; j < NJ; ++j) {
      bf16x8 k0 = *(const bf16x8*)(Kp + (j*16 + lcol) * 64 + lrow4 * 8);
      bf16x8 k1 = *(const bf16x8*)(Kp + (j*16 + lcol) * 64 + 32 + lrow4 * 8);
      acc[j] = __builtin_amdgcn_mfma_f32_16x16x32_bf16(aq0, k0, acc[j], 0, 0, 0);
      acc[j] = __builtin_amdgcn_mfma_f32_16x16x32_bf16(aq1, k1, acc[j], 0, 0, 0);
    }
    float rs[4];
    #pragma unroll
    for (int r = 0; r < 4; ++r) {
      float mx = -3.0e38f;
      #pragma unroll
      for (int j = 0; j < NJ; ++j) mx = fmaxf(mx, acc[j][r]);
      mx = fmaxf(mx, __shfl_xor(mx, 1, 64));
      mx = fmaxf(mx, __shfl_xor(mx, 2, 64));
      mx = fmaxf(mx, __shfl_xor(mx, 4, 64));
      mx = fmaxf(mx, __shfl_xor(mx, 8, 64));
      float sum = 0.f;
      const int prow = wave * 16 + lrow4 * 4 + r;
      #pragma unroll
      for (int j = 0; j < NJ; ++j) {
        float e = __expf((acc[j][r] - mx) * scale);
        sum += e;
        *(u16*)(plb + swz(prow, (j*16 + lcol) * 2)) = f2bf(e);
      }
      sum += __shfl_xor(sum, 1, 64);
      sum += __shfl_xor(sum, 2, 64);
      sum += __shfl_xor(sum, 4, 64);
      sum += __shfl_xor(sum, 8, 64);
      rs[r] = 1.f / sum;
    }
    f32x4 o[4] = {};
    #pragma unroll
    for (int kk = 0; kk < NJ / 2; ++kk) {
      bf16x8 pa = *(const bf16x8*)(plb + swz(wave*16 + lcol, (kk*32 + lrow4*8) * 2));
      #pragma unroll
      for (int d = 0; d < 4; ++d) {
        bf16x8 pb = *(const bf16x8*)(vtb + swz(d*16 + lcol, (kk*32 + lrow4*8) * 2));
        o[d] = __builtin_amdgcn_mfma_f32_16x16x32_bf16(pa, pb, o[d], 0, 0, 0);
      }
    }
    #pragma unroll
    for (int r = 0; r < 4; ++r) {
      int p = start + q0 + lrow4 * 4 + r;
      int rel = p - (widx * 256 - 128);
      float wgt = (rel < 256) ? ((widx == 0) ? 1.f : (float)rel * (1.f / 255.f))
                              : ((widx == 7) ? 1.f : (1.f - (float)(rel - 256) * (1.f / 255.f)));
      float rw = rs[r] * wgt;
      size_t base = (((size_t)(b << 11) + (size_t)p) << 10) + (h << 6);
      #pragma unroll
      for (int d = 0; d < 4; ++d) {
        size_t idx = base + d * 16 + lcol;
        float val = o[d][r] * rw;
        if (phase_ == 0)       ctx[idx] = f2bf(val);
        else if (p >= 1920)    ctx[idx] = f2bf(val);
        else                   ctx[idx] = f2bf(bf2f(ctx[idx]) + val);
      }
    }
  }
}

__global__ __launch_bounds__(256, 1) void attn_kernel(const u16* __restrict__ qg, const u16* __restrict__ kg,
    const u16* __restrict__ vg, u16* __restrict__ ctx, int phase_){
  __shared__ u16 Vt[64 * 512];
  __shared__ u16 Pl[64 * 512];
  int widx = (((int)blockIdx.x >> 6) << 1) + phase_;
  int bh = blockIdx.x & 63;
  int i0 = widx << 8;
  int start = i0 - 128; if (start < 0) start = 0;
  int end = i0 + 384;   if (end > 2048) end = 2048;
  int W = end - start;
  const u16* Qp = qg + (((size_t)bh << 11) + start) * 64;
  const u16* Kp = kg + (((size_t)bh << 11) + start) * 64;
  const u16* Vp = vg + (((size_t)bh << 11) + start) * 64;
  char* vtb = (char*)Vt;
  char* plb = (char*)Pl;
  for (int c = threadIdx.x; c < W * 8; c += 256) {
    int key = c >> 3, d0 = (c & 7) << 3;
    u16x8 vv = *(const u16x8*)(Vp + key * 64 + d0);
    #pragma unroll
    for (int z = 0; z < 8; ++z)
      *(u16*)(vtb + swz(d0 + z, key * 2)) = vv[z];
  }
  __syncthreads();
  if (W == 512) attn_core<32>(Qp, Kp, ctx, vtb, plb, start, widx, phase_, bh);
  else          attn_core<24>(Qp, Kp, ctx, vtb, plb, start, widx, phase_, bh);
}

// ---------------- host
extern "C" void kernel_launch(void* const* d_in, const int* in_sizes, int n_in,
                              void* d_out, int out_size, void* d_ws, size_t ws_size,
                              hipStream_t stream) {
  const float* hidden = (const float*)d_in[0];
  const float* ln1_g  = (const float*)d_in[1];
  const float* ln1_b  = (const float*)d_in[2];
  const float* wq     = (const float*)d_in[3];
  const float* bq     = (const float*)d_in[4];
  const float* wk     = (const float*)d_in[5];
  const float* bk     = (const float*)d_in[6];
  const float* wv     = (const float*)d_in[7];
  const float* bv     = (const float*)d_in[8];
  const float* wproj  = (const float*)d_in[9];
  const float* bproj  = (const float*)d_in[10];
  const float* ln2_g  = (const float*)d_in[11];
  const float* ln2_b  = (const float*)d_in[12];
  const float* w1     = (const float*)d_in[13];
  const float* b1     = (const float*)d_in[14];
  const float* w2     = (const float*)d_in[15];
  const float* b2     = (const float*)d_in[16];

  char* ws = (char*)d_ws;
  u16* xb    = (u16*)(ws + 0);            // 16 MiB (LN1/LN2 out)
  u16* wqkvT = (u16*)(ws + 16777216);     // 6 MiB [3072][1024]
  u16* wpT   = (u16*)(ws + 23068672);     // 2 MiB
  u16* w1T   = (u16*)(ws + 25165824);     // 8 MiB
  u16* w2T   = (u16*)(ws + 33554432);     // 8 MiB
  u16* qb    = (u16*)(ws + 41943040);     // q,k,v contiguous: 3 x 16 MiB
  u16* kb    = (u16*)(ws + 58720256);
  u16* vb    = (u16*)(ws + 75497472);
  u16* ctx   = (u16*)(ws + 92274688);     // 16 MiB
  float* bqkv = (float*)(ws + 92274688);  // aliases ctx start (dead before attn)
  float* res2 = (float*)(ws + 109051904); // 32 MiB f32
  u16* mid   = (u16*)(ws + 41943040);     // 64 MiB, reuses qb..ctx

  dim3 tb(32, 8);
  transpose_cvt<<<dim3(32, 32), tb, 0, stream>>>(wq, wqkvT, 1024, 1024);
  transpose_cvt<<<dim3(32, 32), tb, 0, stream>>>(wk, wqkvT + 1048576, 1024, 1024);
  transpose_cvt<<<dim3(32, 32), tb, 0, stream>>>(wv, wqkvT + 2097152, 1024, 1024);
  transpose_cvt<<<dim3(32, 32), tb, 0, stream>>>(wproj, wpT, 1024, 1024);
  transpose_cvt<<<dim3(128, 32), tb, 0, stream>>>(w1, w1T, 1024, 4096);
  transpose_cvt<<<dim3(32, 128), tb, 0, stream>>>(w2, w2T, 4096, 1024);
  concat3<<<12, 256, 0, stream>>>(bq, bk, bv, bqkv);

  ln_kernel<<<8192, 256, 0, stream>>>(hidden, ln1_g, ln1_b, xb);

  gemm8<0><<<384, 512, 0, stream>>>(xb, wqkvT, bqkv, nullptr, qb, 8192, 3072, 1024);

  attn_kernel<<<256, 256, 0, stream>>>(qb, kb, vb, ctx, 0);
  attn_kernel<<<256, 256, 0, stream>>>(qb, kb, vb, ctx, 1);

  gemmW<<<256, 512, 0, stream>>>(ctx, wpT, bproj, hidden, res2, 8192, 1024, 1024);

  ln_kernel<<<8192, 256, 0, stream>>>(res2, ln2_g, ln2_b, xb);

  gemm8<2><<<512, 512, 0, stream>>>(xb, w1T, b1, nullptr, mid, 8192, 4096, 1024);
  gemmW<<<256, 512, 0, stream>>>(mid, w2T, b2, res2, (float*)d_out, 8192, 1024, 4096);
}